// Round 1
// baseline (498.714 us; speedup 1.0000x reference)
//
#include <hip/hip_runtime.h>
#include <math.h>

#define POOLSZ 7
#define GRID 8          // POOLSZ + 1
#define CCH  256        // channels (fixed by reference setup)

// One block per RoI, one thread per channel.
// Index path (level select, grid coords) uses __fmul_rn/__fadd_rn to match
// numpy's un-fused IEEE f32 arithmetic exactly (floor decisions must not flip).
__global__ __launch_bounds__(256) void fpn_roialign_kernel(
    const float* __restrict__ p2, const float* __restrict__ p3,
    const float* __restrict__ p4, const float* __restrict__ p5,
    const float* __restrict__ rois, const float* __restrict__ im_info,
    float* __restrict__ out,
    int H2, int H3, int H4, int H5, int R)
{
    const int r = blockIdx.x;
    if (r >= R) return;
    const int c = threadIdx.x;

    // ---- per-RoI parameters (broadcast loads; every thread computes) ----
    const float bf = rois[r * 5 + 0];
    const float x1 = rois[r * 5 + 1];
    const float y1 = rois[r * 5 + 2];
    const float x2 = rois[r * 5 + 3];
    const float y2 = rois[r * 5 + 4];

    // h = y2-y1+1, w = x2-x1+1 ; lvl = floor(log(sqrt(h*w)/224)/log(2)+4), clip [2,5]
    const float h = __fadd_rn(__fsub_rn(y2, y1), 1.0f);
    const float w = __fadd_rn(__fsub_rn(x2, x1), 1.0f);
    const float s = __fsqrt_rn(__fmul_rn(h, w));
    // np.float32(np.log(2.0)) == 0x3F317218
    const float LOG2 = __uint_as_float(0x3F317218u);
    float lvlf = floorf(__fadd_rn(__fdiv_rn(logf(__fdiv_rn(s, 224.0f)), LOG2), 4.0f));
    lvlf = fminf(fmaxf(lvlf, 2.0f), 5.0f);
    const int lvl = (int)lvlf;

    const float* feat;
    int H;
    switch (lvl) {
        case 2:  feat = p2; H = H2; break;
        case 3:  feat = p3; H = H3; break;
        case 4:  feat = p4; H = H4; break;
        default: feat = p5; H = H5; break;
    }
    const int W = H;  // square pyramid levels

    // ---- per-RoI sampling grid -> LDS (threads 0..15) ----
    __shared__ float s_wy[GRID], s_wx[GRID];
    __shared__ int   s_y0[GRID], s_y1[GRID], s_x0[GRID], s_x1[GRID];

    if (threadIdx.x < 2 * GRID) {
        const int  i   = threadIdx.x & (GRID - 1);
        const bool isY = threadIdx.x < GRID;
        const float im_h  = im_info[0];
        const float scale = __fdiv_rn((float)H, im_h);   // H == feat.shape[2]
        const float lo = __fmul_rn(isY ? y1 : x1, scale);
        const float hi = __fmul_rn(isY ? y2 : x2, scale);
        const float t  = __fdiv_rn((float)i, (float)(GRID - 1));
        // v = lo + (hi - lo) * t  (no FMA, to match numpy)
        float v = __fadd_rn(lo, __fmul_rn(__fsub_rn(hi, lo), t));
        v = fminf(fmaxf(v, 0.0f), (float)(H - 1));
        const float v0f = floorf(v);
        const int   v0  = (int)v0f;
        const int   v1  = min(v0 + 1, H - 1);
        const float fr  = __fsub_rn(v, v0f);
        if (isY) { s_wy[i] = fr; s_y0[i] = v0; s_y1[i] = v1; }
        else     { s_wx[i] = fr; s_x0[i] = v0; s_x1[i] = v1; }
    }
    __syncthreads();

    // ---- bilinear sample 8x8 grid for channel c, stream 2x2 avg pool ----
    const int b = (int)bf;
    const float* f = feat + ((size_t)(b * CCH + c)) * (size_t)(H * W);
    float* o = out + ((size_t)r * CCH + c) * (POOLSZ * POOLSZ);

    float rowPrev[GRID];
    float rowCur[GRID];

#pragma unroll
    for (int gy = 0; gy < GRID; ++gy) {
        const float* r0 = f + (size_t)s_y0[gy] * W;
        const float* r1 = f + (size_t)s_y1[gy] * W;
        const float wy  = s_wy[gy];
        const float omy = 1.0f - wy;
#pragma unroll
        for (int gx = 0; gx < GRID; ++gx) {
            const int   x0  = s_x0[gx];
            const int   x1i = s_x1[gx];
            const float wx  = s_wx[gx];
            const float omx = 1.0f - wx;
            const float v00 = r0[x0];
            const float v01 = r0[x1i];
            const float v10 = r1[x0];
            const float v11 = r1[x1i];
            // reference form: (1-wy)*((1-wx)*v00 + wx*v01) + wy*((1-wx)*v10 + wx*v11)
            const float top = omx * v00 + wx * v01;
            const float bot = omx * v10 + wx * v11;
            rowCur[gx] = omy * top + wy * bot;
        }
        if (gy > 0) {
            const int py = gy - 1;
#pragma unroll
            for (int px = 0; px < POOLSZ; ++px) {
                o[py * POOLSZ + px] =
                    0.25f * (rowPrev[px] + rowPrev[px + 1] + rowCur[px] + rowCur[px + 1]);
            }
        }
#pragma unroll
        for (int gx = 0; gx < GRID; ++gx) rowPrev[gx] = rowCur[gx];
    }
}

extern "C" void kernel_launch(void* const* d_in, const int* in_sizes, int n_in,
                              void* d_out, int out_size, void* d_ws, size_t ws_size,
                              hipStream_t stream) {
    const float* p2      = (const float*)d_in[0];
    const float* p3      = (const float*)d_in[1];
    const float* p4      = (const float*)d_in[2];
    const float* p5      = (const float*)d_in[3];
    const float* rois    = (const float*)d_in[4];
    const float* im_info = (const float*)d_in[5];
    float* out = (float*)d_out;

    const int R = in_sizes[4] / 5;
    // in_sizes[l] = B*C*H*H with B=1, C=256, square maps
    auto dimOf = [](int sz) {
        int hw = sz / CCH;
        int h = (int)(sqrtf((float)hw) + 0.5f);
        return h;
    };
    const int H2 = dimOf(in_sizes[0]);
    const int H3 = dimOf(in_sizes[1]);
    const int H4 = dimOf(in_sizes[2]);
    const int H5 = dimOf(in_sizes[3]);

    fpn_roialign_kernel<<<R, 256, 0, stream>>>(
        p2, p3, p4, p5, rois, im_info, out, H2, H3, H4, H5, R);
}

// Round 2
// 319.537 us; speedup vs baseline: 1.5607x; 1.5607x over previous
//
#include <hip/hip_runtime.h>
#include <math.h>

#define POOLSZ 7
#define GRIDG 8          // POOLSZ + 1
#define CCH  256         // channels (fixed by reference setup)
#define NBIN 256         // 4 levels x 8x8 spatial tiles

// ---- exact level computation (must match numpy bit-for-bit) ----
__device__ __forceinline__ int roi_level(const float* __restrict__ rois, int r) {
    const float x1 = rois[r * 5 + 1];
    const float y1 = rois[r * 5 + 2];
    const float x2 = rois[r * 5 + 3];
    const float y2 = rois[r * 5 + 4];
    const float h = __fadd_rn(__fsub_rn(y2, y1), 1.0f);
    const float w = __fadd_rn(__fsub_rn(x2, x1), 1.0f);
    const float s = __fsqrt_rn(__fmul_rn(h, w));
    const float LOG2 = __uint_as_float(0x3F317218u);   // np.float32(np.log(2.0))
    float lv = floorf(__fadd_rn(__fdiv_rn(logf(__fdiv_rn(s, 224.0f)), LOG2), 4.0f));
    lv = fminf(fmaxf(lv, 2.0f), 5.0f);
    return (int)lv;
}

// ---- kernel A: bin = (level, 8x8 spatial tile); atomic slot per bin ----
__global__ void bin_kernel(const float* __restrict__ rois,
                           const float* __restrict__ im_info, int R,
                           int* __restrict__ cnt, int* __restrict__ binOf,
                           int* __restrict__ slotOf) {
    const int r = blockIdx.x * blockDim.x + threadIdx.x;
    if (r >= R) return;
    const int lvl = roi_level(rois, r);
    const float cx = 0.5f * (rois[r * 5 + 1] + rois[r * 5 + 3]);
    const float cy = 0.5f * (rois[r * 5 + 2] + rois[r * 5 + 4]);
    const float ih = im_info[0];
    const float iw = im_info[1];
    const int tx = min(7, max(0, (int)(cx * 8.0f / iw)));
    const int ty = min(7, max(0, (int)(cy * 8.0f / ih)));
    const int bin = (lvl - 2) * 64 + ty * 8 + tx;
    binOf[r] = bin;
    slotOf[r] = atomicAdd(&cnt[bin], 1);
}

// ---- kernel B: exclusive scan of 256 bin counts (single block) ----
__global__ void scan_kernel(const int* __restrict__ cnt, int* __restrict__ off) {
    __shared__ int tmp[NBIN];
    const int t = threadIdx.x;
    const int my = cnt[t];
    tmp[t] = my;
    __syncthreads();
    for (int s = 1; s < NBIN; s <<= 1) {
        int v = (t >= s) ? tmp[t - s] : 0;
        __syncthreads();
        tmp[t] += v;
        __syncthreads();
    }
    off[t] = tmp[t] - my;   // exclusive
}

// ---- kernel C: scatter RoI indices into sorted order ----
__global__ void scatter_kernel(const int* __restrict__ binOf,
                               const int* __restrict__ slotOf,
                               const int* __restrict__ off,
                               int* __restrict__ sorted, int R) {
    const int r = blockIdx.x * blockDim.x + threadIdx.x;
    if (r >= R) return;
    sorted[off[binOf[r]] + slotOf[r]] = r;
}

// ---- main kernel: one block per (sorted) RoI, one thread per channel ----
__global__ __launch_bounds__(256) void fpn_roialign_kernel(
    const float* __restrict__ p2, const float* __restrict__ p3,
    const float* __restrict__ p4, const float* __restrict__ p5,
    const float* __restrict__ rois, const float* __restrict__ im_info,
    float* __restrict__ out, const int* __restrict__ order,
    int H2, int H3, int H4, int H5, int R)
{
    // bijective XCD chunk swizzle: consecutive sorted RoIs stay on one XCD
    const int n = blockIdx.x;
    const int q = R / 8, rem = R % 8;
    const int xcd = n % 8, idx = n / 8;
    const int nsw = (xcd < rem ? xcd * (q + 1) : rem * (q + 1) + (xcd - rem) * q) + idx;
    const int r = order ? order[nsw] : nsw;
    const int c = threadIdx.x;

    const float bf = rois[r * 5 + 0];
    const float x1 = rois[r * 5 + 1];
    const float y1 = rois[r * 5 + 2];
    const float x2 = rois[r * 5 + 3];
    const float y2 = rois[r * 5 + 4];

    const int lvl = roi_level(rois, r);
    const float* feat;
    int H;
    switch (lvl) {
        case 2:  feat = p2; H = H2; break;
        case 3:  feat = p3; H = H3; break;
        case 4:  feat = p4; H = H4; break;
        default: feat = p5; H = H5; break;
    }
    const int W = H;  // square pyramid levels

    __shared__ float s_wy[GRIDG], s_wx[GRIDG];
    __shared__ int   s_y0[GRIDG], s_y1[GRIDG], s_x0[GRIDG], s_x1[GRIDG];
    __shared__ float s_out[CCH * POOLSZ * POOLSZ];   // 50176 B

    if (threadIdx.x < 2 * GRIDG) {
        const int  i   = threadIdx.x & (GRIDG - 1);
        const bool isY = threadIdx.x < GRIDG;
        const float im_h  = im_info[0];
        const float scale = __fdiv_rn((float)H, im_h);
        const float lo = __fmul_rn(isY ? y1 : x1, scale);
        const float hi = __fmul_rn(isY ? y2 : x2, scale);
        const float t  = __fdiv_rn((float)i, (float)(GRIDG - 1));
        float v = __fadd_rn(lo, __fmul_rn(__fsub_rn(hi, lo), t));  // no FMA
        v = fminf(fmaxf(v, 0.0f), (float)(H - 1));
        const float v0f = floorf(v);
        const int   v0  = (int)v0f;
        const int   v1  = min(v0 + 1, H - 1);
        const float fr  = __fsub_rn(v, v0f);
        if (isY) { s_wy[i] = fr; s_y0[i] = v0; s_y1[i] = v1; }
        else     { s_wx[i] = fr; s_x0[i] = v0; s_x1[i] = v1; }
    }
    __syncthreads();

    const int b = (int)bf;
    const float* f = feat + ((size_t)(b * CCH + c)) * (size_t)(H * W);
    float* so = s_out + c * (POOLSZ * POOLSZ);

    float rowPrev[GRIDG];
    float rowCur[GRIDG];

#pragma unroll
    for (int gy = 0; gy < GRIDG; ++gy) {
        const float* r0 = f + (size_t)s_y0[gy] * W;
        const float* r1 = f + (size_t)s_y1[gy] * W;
        const float wy  = s_wy[gy];
        const float omy = 1.0f - wy;
#pragma unroll
        for (int gx = 0; gx < GRIDG; ++gx) {
            const int   x0  = s_x0[gx];
            const int   x1i = s_x1[gx];
            const float wx  = s_wx[gx];
            const float omx = 1.0f - wx;
            const float v00 = r0[x0];
            const float v01 = r0[x1i];
            const float v10 = r1[x0];
            const float v11 = r1[x1i];
            const float top = omx * v00 + wx * v01;
            const float bot = omx * v10 + wx * v11;
            rowCur[gx] = omy * top + wy * bot;
        }
        if (gy > 0) {
            const int py = gy - 1;
#pragma unroll
            for (int px = 0; px < POOLSZ; ++px) {
                so[py * POOLSZ + px] =
                    0.25f * (rowPrev[px] + rowPrev[px + 1] + rowCur[px] + rowCur[px + 1]);
            }
        }
#pragma unroll
        for (int gx = 0; gx < GRIDG; ++gx) rowPrev[gx] = rowCur[gx];
    }

    // coalesced, nontemporal burst write: 12544 dwords = 49 per thread
    __syncthreads();
    float* obase = out + (size_t)r * (CCH * POOLSZ * POOLSZ);
#pragma unroll
    for (int i = 0; i < POOLSZ * POOLSZ; ++i) {
        const int k = i * CCH + threadIdx.x;
        __builtin_nontemporal_store(s_out[k], obase + k);
    }
}

extern "C" void kernel_launch(void* const* d_in, const int* in_sizes, int n_in,
                              void* d_out, int out_size, void* d_ws, size_t ws_size,
                              hipStream_t stream) {
    const float* p2      = (const float*)d_in[0];
    const float* p3      = (const float*)d_in[1];
    const float* p4      = (const float*)d_in[2];
    const float* p5      = (const float*)d_in[3];
    const float* rois    = (const float*)d_in[4];
    const float* im_info = (const float*)d_in[5];
    float* out = (float*)d_out;

    const int R = in_sizes[4] / 5;
    auto dimOf = [](int sz) {
        int hw = sz / CCH;
        return (int)(sqrtf((float)hw) + 0.5f);
    };
    const int H2 = dimOf(in_sizes[0]);
    const int H3 = dimOf(in_sizes[1]);
    const int H4 = dimOf(in_sizes[2]);
    const int H5 = dimOf(in_sizes[3]);

    // ws layout (ints): cnt[256] | off[256] | binOf[R] | slotOf[R] | sorted[R]
    const size_t need = (size_t)(2 * NBIN + 3 * R) * sizeof(int);
    int* wsI = (int*)d_ws;
    const int* order = nullptr;
    if (ws_size >= need) {
        int* cnt    = wsI;
        int* off    = wsI + NBIN;
        int* binOf  = wsI + 2 * NBIN;
        int* slotOf = wsI + 2 * NBIN + R;
        int* sorted = wsI + 2 * NBIN + 2 * R;
        hipMemsetAsync(cnt, 0, NBIN * sizeof(int), stream);
        bin_kernel<<<(R + 255) / 256, 256, 0, stream>>>(rois, im_info, R, cnt, binOf, slotOf);
        scan_kernel<<<1, NBIN, 0, stream>>>(cnt, off);
        scatter_kernel<<<(R + 255) / 256, 256, 0, stream>>>(binOf, slotOf, off, sorted, R);
        order = sorted;
    }

    fpn_roialign_kernel<<<R, 256, 0, stream>>>(
        p2, p3, p4, p5, rois, im_info, out, order, H2, H3, H4, H5, R);
}

// Round 3
// 148.325 us; speedup vs baseline: 3.3623x; 2.1543x over previous
//
#include <hip/hip_runtime.h>
#include <math.h>

#define POOLSZ 7
#define GRIDG 8          // POOLSZ + 1
#define CCH  256         // channels (fixed by reference setup)
#define NBIN 256         // 4 levels x 8x8 spatial tiles

// ---- exact level computation (must match numpy bit-for-bit) ----
__device__ __forceinline__ int roi_level(const float* __restrict__ rois, int r) {
    const float x1 = rois[r * 5 + 1];
    const float y1 = rois[r * 5 + 2];
    const float x2 = rois[r * 5 + 3];
    const float y2 = rois[r * 5 + 4];
    const float h = __fadd_rn(__fsub_rn(y2, y1), 1.0f);
    const float w = __fadd_rn(__fsub_rn(x2, x1), 1.0f);
    const float s = __fsqrt_rn(__fmul_rn(h, w));
    const float LOG2 = __uint_as_float(0x3F317218u);   // np.float32(np.log(2.0))
    float lv = floorf(__fadd_rn(__fdiv_rn(logf(__fdiv_rn(s, 224.0f)), LOG2), 4.0f));
    lv = fminf(fmaxf(lv, 2.0f), 5.0f);
    return (int)lv;
}

// ---- kernel A: bin = (level, 8x8 spatial tile); atomic slot per bin ----
__global__ void bin_kernel(const float* __restrict__ rois,
                           const float* __restrict__ im_info, int R,
                           int* __restrict__ cnt, int* __restrict__ binOf,
                           int* __restrict__ slotOf) {
    const int r = blockIdx.x * blockDim.x + threadIdx.x;
    if (r >= R) return;
    const int lvl = roi_level(rois, r);
    const float cx = 0.5f * (rois[r * 5 + 1] + rois[r * 5 + 3]);
    const float cy = 0.5f * (rois[r * 5 + 2] + rois[r * 5 + 4]);
    const float ih = im_info[0];
    const float iw = im_info[1];
    const int tx = min(7, max(0, (int)(cx * 8.0f / iw)));
    const int ty = min(7, max(0, (int)(cy * 8.0f / ih)));
    const int bin = (lvl - 2) * 64 + ty * 8 + tx;
    binOf[r] = bin;
    slotOf[r] = atomicAdd(&cnt[bin], 1);
}

// ---- kernel B: exclusive scan of 256 bin counts (single block) ----
__global__ void scan_kernel(const int* __restrict__ cnt, int* __restrict__ off) {
    __shared__ int tmp[NBIN];
    const int t = threadIdx.x;
    const int my = cnt[t];
    tmp[t] = my;
    __syncthreads();
    for (int s = 1; s < NBIN; s <<= 1) {
        int v = (t >= s) ? tmp[t - s] : 0;
        __syncthreads();
        tmp[t] += v;
        __syncthreads();
    }
    off[t] = tmp[t] - my;   // exclusive
}

// ---- kernel C: scatter RoI indices into sorted order ----
__global__ void scatter_kernel(const int* __restrict__ binOf,
                               const int* __restrict__ slotOf,
                               const int* __restrict__ off,
                               int* __restrict__ sorted, int R) {
    const int r = blockIdx.x * blockDim.x + threadIdx.x;
    if (r >= R) return;
    sorted[off[binOf[r]] + slotOf[r]] = r;
}

// ---- main kernel: one block per RoI; lane = (gy,gx) sample point;
//      each of the 4 waves loops over 64 channels ----
__global__ __launch_bounds__(256) void fpn_roialign_kernel(
    const float* __restrict__ p2, const float* __restrict__ p3,
    const float* __restrict__ p4, const float* __restrict__ p5,
    const float* __restrict__ rois, const float* __restrict__ im_info,
    float* __restrict__ out, const int* __restrict__ order,
    int H2, int H3, int H4, int H5, int R)
{
    // bijective XCD chunk swizzle: consecutive sorted RoIs stay on one XCD
    const int n = blockIdx.x;
    const int q = R / 8, rem = R % 8;
    const int xcd = n % 8, idx = n / 8;
    const int nsw = (xcd < rem ? xcd * (q + 1) : rem * (q + 1) + (xcd - rem) * q) + idx;
    const int r = order ? order[nsw] : nsw;

    const float bf = rois[r * 5 + 0];
    const float x1 = rois[r * 5 + 1];
    const float y1 = rois[r * 5 + 2];
    const float x2 = rois[r * 5 + 3];
    const float y2 = rois[r * 5 + 4];

    const int lvl = roi_level(rois, r);
    const float* feat;
    int H;
    switch (lvl) {
        case 2:  feat = p2; H = H2; break;
        case 3:  feat = p3; H = H3; break;
        case 4:  feat = p4; H = H4; break;
        default: feat = p5; H = H5; break;
    }
    const int W = H;  // square pyramid levels

    const int wv  = threadIdx.x >> 6;   // wave id 0..3
    const int lid = threadIdx.x & 63;
    const int gy  = lid >> 3;
    const int gx  = lid & 7;

    // per-lane sampling coords — exact numpy arithmetic (no FMA on index path)
    const float im_h  = im_info[0];
    const float scale = __fdiv_rn((float)H, im_h);
    const float ylo = __fmul_rn(y1, scale), yhi = __fmul_rn(y2, scale);
    const float xlo = __fmul_rn(x1, scale), xhi = __fmul_rn(x2, scale);
    float ty = __fadd_rn(ylo, __fmul_rn(__fsub_rn(yhi, ylo),
                                        __fdiv_rn((float)gy, (float)(GRIDG - 1))));
    ty = fminf(fmaxf(ty, 0.0f), (float)(H - 1));
    float tx = __fadd_rn(xlo, __fmul_rn(__fsub_rn(xhi, xlo),
                                        __fdiv_rn((float)gx, (float)(GRIDG - 1))));
    tx = fminf(fmaxf(tx, 0.0f), (float)(W - 1));
    const float y0f = floorf(ty), x0f = floorf(tx);
    const int   y0  = (int)y0f,   x0  = (int)x0f;
    const int   y1i = min(y0 + 1, H - 1);
    const int   x1i = min(x0 + 1, W - 1);
    const float wy  = __fsub_rn(ty, y0f);
    const float wx  = __fsub_rn(tx, x0f);
    const float omy = 1.0f - wy;
    const float omx = 1.0f - wx;

    const int b = (int)bf;
    const size_t plane = (size_t)H * W;
    const float* fbase = feat + (size_t)(b * CCH + wv * 64) * plane;
    const int o00 = y0  * W + x0;
    const int o01 = y0  * W + x1i;
    const int o10 = y1i * W + x0;
    const int o11 = y1i * W + x1i;

    float* obase = out + (size_t)r * (CCH * POOLSZ * POOLSZ)
                       + (size_t)(wv * 64) * (POOLSZ * POOLSZ);
    const bool wr  = (gy < POOLSZ) && (gx < POOLSZ);
    const int oidx = gy * POOLSZ + gx;

#pragma unroll 4
    for (int k = 0; k < 64; ++k) {
        const float* f = fbase + (size_t)k * plane;
        const float v00 = f[o00];
        const float v01 = f[o01];
        const float v10 = f[o10];
        const float v11 = f[o11];
        // reference form: (1-wy)*((1-wx)*v00 + wx*v01) + wy*((1-wx)*v10 + wx*v11)
        const float v = omy * (omx * v00 + wx * v01) + wy * (omx * v10 + wx * v11);
        // 2x2 stride-1 avg pool via cross-lane: lanes l, l+8, l+1, l+9
        const float vb  = __shfl_down(v, 8);
        const float vr  = __shfl_down(v, 1);
        const float vbr = __shfl_down(v, 9);
        if (wr) obase[k * (POOLSZ * POOLSZ) + oidx] =
            0.25f * (((v + vb) + vr) + vbr);
    }
}

extern "C" void kernel_launch(void* const* d_in, const int* in_sizes, int n_in,
                              void* d_out, int out_size, void* d_ws, size_t ws_size,
                              hipStream_t stream) {
    const float* p2      = (const float*)d_in[0];
    const float* p3      = (const float*)d_in[1];
    const float* p4      = (const float*)d_in[2];
    const float* p5      = (const float*)d_in[3];
    const float* rois    = (const float*)d_in[4];
    const float* im_info = (const float*)d_in[5];
    float* out = (float*)d_out;

    const int R = in_sizes[4] / 5;
    auto dimOf = [](int sz) {
        int hw = sz / CCH;
        return (int)(sqrtf((float)hw) + 0.5f);
    };
    const int H2 = dimOf(in_sizes[0]);
    const int H3 = dimOf(in_sizes[1]);
    const int H4 = dimOf(in_sizes[2]);
    const int H5 = dimOf(in_sizes[3]);

    // ws layout (ints): cnt[256] | off[256] | binOf[R] | slotOf[R] | sorted[R]
    const size_t need = (size_t)(2 * NBIN + 3 * R) * sizeof(int);
    int* wsI = (int*)d_ws;
    const int* order = nullptr;
    if (ws_size >= need) {
        int* cnt    = wsI;
        int* off    = wsI + NBIN;
        int* binOf  = wsI + 2 * NBIN;
        int* slotOf = wsI + 2 * NBIN + R;
        int* sorted = wsI + 2 * NBIN + 2 * R;
        hipMemsetAsync(cnt, 0, NBIN * sizeof(int), stream);
        bin_kernel<<<(R + 255) / 256, 256, 0, stream>>>(rois, im_info, R, cnt, binOf, slotOf);
        scan_kernel<<<1, NBIN, 0, stream>>>(cnt, off);
        scatter_kernel<<<(R + 255) / 256, 256, 0, stream>>>(binOf, slotOf, off, sorted, R);
        order = sorted;
    }

    fpn_roialign_kernel<<<R, 256, 0, stream>>>(
        p2, p3, p4, p5, rois, im_info, out, order, H2, H3, H4, H5, R);
}

// Round 4
// 88.629 us; speedup vs baseline: 5.6270x; 1.6736x over previous
//
#include <hip/hip_runtime.h>
#include <math.h>

#define POOLSZ 7
#define GRIDG 8          // POOLSZ + 1
#define CCH  256         // channels (fixed by reference setup)
#define NBIN 256         // 4 levels x 8x8 spatial tiles
#define OPP  (POOLSZ * POOLSZ)   // 49
#define SPAD 51          // LDS stride for staged output (odd -> conflict-free)

// ---- exact level computation (must match numpy bit-for-bit) ----
__device__ __forceinline__ int roi_level(const float* __restrict__ rois, int r) {
    const float x1 = rois[r * 5 + 1];
    const float y1 = rois[r * 5 + 2];
    const float x2 = rois[r * 5 + 3];
    const float y2 = rois[r * 5 + 4];
    const float h = __fadd_rn(__fsub_rn(y2, y1), 1.0f);
    const float w = __fadd_rn(__fsub_rn(x2, x1), 1.0f);
    const float s = __fsqrt_rn(__fmul_rn(h, w));
    const float LOG2 = __uint_as_float(0x3F317218u);   // np.float32(np.log(2.0))
    float lv = floorf(__fadd_rn(__fdiv_rn(logf(__fdiv_rn(s, 224.0f)), LOG2), 4.0f));
    lv = fminf(fmaxf(lv, 2.0f), 5.0f);
    return (int)lv;
}

// ---- kernel A: bin = (level, 8x8 spatial tile); atomic slot per bin ----
__global__ void bin_kernel(const float* __restrict__ rois,
                           const float* __restrict__ im_info, int R,
                           int* __restrict__ cnt, int* __restrict__ binOf,
                           int* __restrict__ slotOf) {
    const int r = blockIdx.x * blockDim.x + threadIdx.x;
    if (r >= R) return;
    const int lvl = roi_level(rois, r);
    const float cx = 0.5f * (rois[r * 5 + 1] + rois[r * 5 + 3]);
    const float cy = 0.5f * (rois[r * 5 + 2] + rois[r * 5 + 4]);
    const float ih = im_info[0];
    const float iw = im_info[1];
    const int tx = min(7, max(0, (int)(cx * 8.0f / iw)));
    const int ty = min(7, max(0, (int)(cy * 8.0f / ih)));
    const int bin = (lvl - 2) * 64 + ty * 8 + tx;
    binOf[r] = bin;
    slotOf[r] = atomicAdd(&cnt[bin], 1);
}

// ---- kernel B: exclusive scan of 256 bin counts (single block) ----
__global__ void scan_kernel(const int* __restrict__ cnt, int* __restrict__ off) {
    __shared__ int tmp[NBIN];
    const int t = threadIdx.x;
    const int my = cnt[t];
    tmp[t] = my;
    __syncthreads();
    for (int s = 1; s < NBIN; s <<= 1) {
        int v = (t >= s) ? tmp[t - s] : 0;
        __syncthreads();
        tmp[t] += v;
        __syncthreads();
    }
    off[t] = tmp[t] - my;   // exclusive
}

// ---- kernel C: scatter RoI indices into sorted order ----
__global__ void scatter_kernel(const int* __restrict__ binOf,
                               const int* __restrict__ slotOf,
                               const int* __restrict__ off,
                               int* __restrict__ sorted, int R) {
    const int r = blockIdx.x * blockDim.x + threadIdx.x;
    if (r >= R) return;
    sorted[off[binOf[r]] + slotOf[r]] = r;
}

// ---- transpose: [C, HW] -> [HW, C], 64x64 tiles, both sides coalesced ----
__global__ __launch_bounds__(256) void transpose_kernel(
    const float* __restrict__ in, float* __restrict__ outT, int HW) {
    __shared__ float tile[64][65];
    const int t = threadIdx.x;
    const int lane = t & 63, row4 = t >> 6;
    const int pbase = blockIdx.x * 64;
    const int cbase = blockIdx.y * 64;
#pragma unroll
    for (int i = 0; i < 16; ++i) {
        const int c = i * 4 + row4;
        tile[c][lane] = in[(size_t)(cbase + c) * HW + pbase + lane];
    }
    __syncthreads();
#pragma unroll
    for (int i = 0; i < 16; ++i) {
        const int p = i * 4 + row4;
        outT[(size_t)(pbase + p) * CCH + cbase + lane] = tile[lane][p];
    }
}

// ---- main kernel (transposed layout): one block per RoI, lane = channel.
//      Every gather is 256 consecutive floats; weights are loop-uniform. ----
__global__ __launch_bounds__(256) void fpn_main_t(
    const float* __restrict__ t2, const float* __restrict__ t3,
    const float* __restrict__ t4, const float* __restrict__ t5,
    const float* __restrict__ rois, const float* __restrict__ im_info,
    float* __restrict__ out, const int* __restrict__ order,
    int H2, int H3, int H4, int H5, int R)
{
    // bijective XCD chunk swizzle
    const int n = blockIdx.x;
    const int q = R / 8, rem = R % 8;
    const int xcd = n % 8, idx = n / 8;
    const int nsw = (xcd < rem ? xcd * (q + 1) : rem * (q + 1) + (xcd - rem) * q) + idx;
    const int r = order ? order[nsw] : nsw;
    const int t = threadIdx.x;   // channel

    const float x1 = rois[r * 5 + 1];
    const float y1 = rois[r * 5 + 2];
    const float x2 = rois[r * 5 + 3];
    const float y2 = rois[r * 5 + 4];

    const int lvl = roi_level(rois, r);
    const float* feat;
    int H;
    switch (lvl) {
        case 2:  feat = t2; H = H2; break;
        case 3:  feat = t3; H = H3; break;
        case 4:  feat = t4; H = H4; break;
        default: feat = t5; H = H5; break;
    }
    const int W = H;

    // grid coords (exact numpy arithmetic; every thread computes all 8)
    const float im_h  = im_info[0];
    const float scale = __fdiv_rn((float)H, im_h);
    const float ylo = __fmul_rn(y1, scale), yhi = __fmul_rn(y2, scale);
    const float xlo = __fmul_rn(x1, scale), xhi = __fmul_rn(x2, scale);

    float wy[GRIDG], wx[GRIDG];
    int yoff[GRIDG], dy[GRIDG], xoff[GRIDG], dx[GRIDG];
#pragma unroll
    for (int i = 0; i < GRIDG; ++i) {
        const float tf = __fdiv_rn((float)i, (float)(GRIDG - 1));
        float ty = __fadd_rn(ylo, __fmul_rn(__fsub_rn(yhi, ylo), tf));
        ty = fminf(fmaxf(ty, 0.0f), (float)(H - 1));
        const float y0f = floorf(ty);
        const int   y0  = (int)y0f;
        yoff[i] = y0 * W * CCH;
        dy[i]   = (min(y0 + 1, H - 1) - y0) * W * CCH;
        wy[i]   = __fsub_rn(ty, y0f);

        float tx = __fadd_rn(xlo, __fmul_rn(__fsub_rn(xhi, xlo), tf));
        tx = fminf(fmaxf(tx, 0.0f), (float)(W - 1));
        const float x0f = floorf(tx);
        const int   x0  = (int)x0f;
        xoff[i] = x0 * CCH;
        dx[i]   = (min(x0 + 1, W - 1) - x0) * CCH;
        wx[i]   = __fsub_rn(tx, x0f);
    }

    __shared__ float s_out[CCH * SPAD];   // [channel][51] -> 52 KB

    float rowPrev[GRIDG], rowCur[GRIDG];
#pragma unroll
    for (int gy = 0; gy < GRIDG; ++gy) {
        const float* base = feat + yoff[gy] + t;
        const int dyg = dy[gy];
        const float wyg = wy[gy];
        const float omy = 1.0f - wyg;
#pragma unroll
        for (int gx = 0; gx < GRIDG; ++gx) {
            const float* qp = base + xoff[gx];
            const int dxg = dx[gx];
            const float v00 = qp[0];
            const float v01 = qp[dxg];
            const float v10 = qp[dyg];
            const float v11 = qp[dyg + dxg];
            const float wxg = wx[gx];
            const float omx = 1.0f - wxg;
            rowCur[gx] = omy * (omx * v00 + wxg * v01) + wyg * (omx * v10 + wxg * v11);
        }
        if (gy > 0) {
            const int py = gy - 1;
#pragma unroll
            for (int px = 0; px < POOLSZ; ++px) {
                s_out[t * SPAD + py * POOLSZ + px] =
                    0.25f * (rowPrev[px] + rowPrev[px + 1] + rowCur[px] + rowCur[px + 1]);
            }
        }
#pragma unroll
        for (int gx = 0; gx < GRIDG; ++gx) rowPrev[gx] = rowCur[gx];
    }

    __syncthreads();
    // coalesced c-major burst: k = c*49+pp ; c = k/49 via magic mul
    float* obase = out + (size_t)r * (CCH * OPP);
#pragma unroll
    for (int i = 0; i < OPP; ++i) {
        const unsigned k = (unsigned)(i * CCH + t);
        const unsigned c = (k * 21400u) >> 20;        // k/49, exact for k<12544
        const unsigned pp = k - c * 49u;
        __builtin_nontemporal_store(s_out[c * SPAD + pp], obase + k);
    }
}

// ---- fallback (round-3 kernel): used only if d_ws can't hold transposes ----
__global__ __launch_bounds__(256) void fpn_roialign_kernel(
    const float* __restrict__ p2, const float* __restrict__ p3,
    const float* __restrict__ p4, const float* __restrict__ p5,
    const float* __restrict__ rois, const float* __restrict__ im_info,
    float* __restrict__ out, const int* __restrict__ order,
    int H2, int H3, int H4, int H5, int R)
{
    const int n = blockIdx.x;
    const int q = R / 8, rem = R % 8;
    const int xcd = n % 8, idx = n / 8;
    const int nsw = (xcd < rem ? xcd * (q + 1) : rem * (q + 1) + (xcd - rem) * q) + idx;
    const int r = order ? order[nsw] : nsw;

    const float bf = rois[r * 5 + 0];
    const float x1 = rois[r * 5 + 1];
    const float y1 = rois[r * 5 + 2];
    const float x2 = rois[r * 5 + 3];
    const float y2 = rois[r * 5 + 4];

    const int lvl = roi_level(rois, r);
    const float* feat;
    int H;
    switch (lvl) {
        case 2:  feat = p2; H = H2; break;
        case 3:  feat = p3; H = H3; break;
        case 4:  feat = p4; H = H4; break;
        default: feat = p5; H = H5; break;
    }
    const int W = H;
    const int wv  = threadIdx.x >> 6;
    const int lid = threadIdx.x & 63;
    const int gy  = lid >> 3;
    const int gx  = lid & 7;

    const float im_h  = im_info[0];
    const float scale = __fdiv_rn((float)H, im_h);
    const float ylo = __fmul_rn(y1, scale), yhi = __fmul_rn(y2, scale);
    const float xlo = __fmul_rn(x1, scale), xhi = __fmul_rn(x2, scale);
    float ty = __fadd_rn(ylo, __fmul_rn(__fsub_rn(yhi, ylo),
                                        __fdiv_rn((float)gy, (float)(GRIDG - 1))));
    ty = fminf(fmaxf(ty, 0.0f), (float)(H - 1));
    float tx = __fadd_rn(xlo, __fmul_rn(__fsub_rn(xhi, xlo),
                                        __fdiv_rn((float)gx, (float)(GRIDG - 1))));
    tx = fminf(fmaxf(tx, 0.0f), (float)(W - 1));
    const float y0f = floorf(ty), x0f = floorf(tx);
    const int   y0  = (int)y0f,   x0  = (int)x0f;
    const int   y1i = min(y0 + 1, H - 1);
    const int   x1i = min(x0 + 1, W - 1);
    const float wyv = __fsub_rn(ty, y0f);
    const float wxv = __fsub_rn(tx, x0f);
    const float omy = 1.0f - wyv;
    const float omx = 1.0f - wxv;

    const int b = (int)bf;
    const size_t plane = (size_t)H * W;
    const float* fbase = feat + (size_t)(b * CCH + wv * 64) * plane;
    const int o00 = y0  * W + x0;
    const int o01 = y0  * W + x1i;
    const int o10 = y1i * W + x0;
    const int o11 = y1i * W + x1i;

    float* obase = out + (size_t)r * (CCH * OPP) + (size_t)(wv * 64) * OPP;
    const bool wr  = (gy < POOLSZ) && (gx < POOLSZ);
    const int oidx = gy * POOLSZ + gx;

#pragma unroll 4
    for (int k = 0; k < 64; ++k) {
        const float* f = fbase + (size_t)k * plane;
        const float v00 = f[o00];
        const float v01 = f[o01];
        const float v10 = f[o10];
        const float v11 = f[o11];
        const float v = omy * (omx * v00 + wxv * v01) + wyv * (omx * v10 + wxv * v11);
        const float vb  = __shfl_down(v, 8);
        const float vr  = __shfl_down(v, 1);
        const float vbr = __shfl_down(v, 9);
        if (wr) obase[k * OPP + oidx] = 0.25f * (((v + vb) + vr) + vbr);
    }
}

extern "C" void kernel_launch(void* const* d_in, const int* in_sizes, int n_in,
                              void* d_out, int out_size, void* d_ws, size_t ws_size,
                              hipStream_t stream) {
    const float* p2      = (const float*)d_in[0];
    const float* p3      = (const float*)d_in[1];
    const float* p4      = (const float*)d_in[2];
    const float* p5      = (const float*)d_in[3];
    const float* rois    = (const float*)d_in[4];
    const float* im_info = (const float*)d_in[5];
    float* out = (float*)d_out;

    const int R = in_sizes[4] / 5;
    auto dimOf = [](int sz) {
        int hw = sz / CCH;
        return (int)(sqrtf((float)hw) + 0.5f);
    };
    const int H2 = dimOf(in_sizes[0]);
    const int H3 = dimOf(in_sizes[1]);
    const int H4 = dimOf(in_sizes[2]);
    const int H5 = dimOf(in_sizes[3]);
    const size_t HW2 = (size_t)H2 * H2, HW3 = (size_t)H3 * H3;
    const size_t HW4 = (size_t)H4 * H4, HW5 = (size_t)H5 * H5;

    // ws layout: sort ints | t2 | t3 | t4 | t5 (floats, 256-byte aligned)
    const size_t sortBytes = (size_t)(2 * NBIN + 3 * R) * sizeof(int);
    const size_t sortPad   = (sortBytes + 255) & ~(size_t)255;
    const size_t transBytes = (HW2 + HW3 + HW4 + HW5) * CCH * sizeof(float);
    const bool canSort  = ws_size >= sortBytes;
    const bool canTrans = ws_size >= sortPad + transBytes;

    const int* order = nullptr;
    if (canSort) {
        int* wsI    = (int*)d_ws;
        int* cnt    = wsI;
        int* off    = wsI + NBIN;
        int* binOf  = wsI + 2 * NBIN;
        int* slotOf = wsI + 2 * NBIN + R;
        int* sorted = wsI + 2 * NBIN + 2 * R;
        hipMemsetAsync(cnt, 0, NBIN * sizeof(int), stream);
        bin_kernel<<<(R + 255) / 256, 256, 0, stream>>>(rois, im_info, R, cnt, binOf, slotOf);
        scan_kernel<<<1, NBIN, 0, stream>>>(cnt, off);
        scatter_kernel<<<(R + 255) / 256, 256, 0, stream>>>(binOf, slotOf, off, sorted, R);
        order = sorted;
    }

    if (canTrans) {
        float* t2 = (float*)((char*)d_ws + sortPad);
        float* t3 = t2 + HW2 * CCH;
        float* t4 = t3 + HW3 * CCH;
        float* t5 = t4 + HW4 * CCH;
        transpose_kernel<<<dim3((unsigned)(HW2 / 64), 4), 256, 0, stream>>>(p2, t2, (int)HW2);
        transpose_kernel<<<dim3((unsigned)(HW3 / 64), 4), 256, 0, stream>>>(p3, t3, (int)HW3);
        transpose_kernel<<<dim3((unsigned)(HW4 / 64), 4), 256, 0, stream>>>(p4, t4, (int)HW4);
        transpose_kernel<<<dim3((unsigned)(HW5 / 64), 4), 256, 0, stream>>>(p5, t5, (int)HW5);
        fpn_main_t<<<R, 256, 0, stream>>>(
            t2, t3, t4, t5, rois, im_info, out, order, H2, H3, H4, H5, R);
    } else {
        fpn_roialign_kernel<<<R, 256, 0, stream>>>(
            p2, p3, p4, p5, rois, im_info, out, order, H2, H3, H4, H5, R);
    }
}

// Round 5
// 65.953 us; speedup vs baseline: 7.5617x; 1.3438x over previous
//
#include <hip/hip_runtime.h>
#include <hip/hip_fp16.h>
#include <math.h>

#define POOLSZ 7
#define GRIDG 8          // POOLSZ + 1
#define CCH  256         // channels (fixed by reference setup)
#define NBIN 256         // 4 levels x 8x8 spatial tiles
#define OPP  (POOLSZ * POOLSZ)   // 49
#define SPAD 51          // LDS stride for staged output (odd -> conflict-free)
#define MAXPER 8         // max RoIs per thread in fused sort (R <= 8192)

// ---- exact level computation (must match numpy bit-for-bit) ----
__device__ __forceinline__ int roi_level(const float* __restrict__ rois, int r) {
    const float x1 = rois[r * 5 + 1];
    const float y1 = rois[r * 5 + 2];
    const float x2 = rois[r * 5 + 3];
    const float y2 = rois[r * 5 + 4];
    const float h = __fadd_rn(__fsub_rn(y2, y1), 1.0f);
    const float w = __fadd_rn(__fsub_rn(x2, x1), 1.0f);
    const float s = __fsqrt_rn(__fmul_rn(h, w));
    const float LOG2 = __uint_as_float(0x3F317218u);   // np.float32(np.log(2.0))
    float lv = floorf(__fadd_rn(__fdiv_rn(logf(__fdiv_rn(s, 224.0f)), LOG2), 4.0f));
    lv = fminf(fmaxf(lv, 2.0f), 5.0f);
    return (int)lv;
}

// ---- fused sort: bin by (level, 8x8 tile), scan, scatter — one block ----
__global__ __launch_bounds__(1024) void sort_all_kernel(
    const float* __restrict__ rois, const float* __restrict__ im_info,
    int R, int* __restrict__ sorted)
{
    __shared__ int cnt[NBIN];
    __shared__ int tmp[NBIN];
    const int t = threadIdx.x;
    if (t < NBIN) cnt[t] = 0;
    __syncthreads();

    int myR[MAXPER], myBin[MAXPER], mySlot[MAXPER];
    int m = 0;
    const float ih = im_info[0], iw = im_info[1];
    for (int r = t; r < R && m < MAXPER; r += 1024) {
        const int lvl = roi_level(rois, r);
        const float cx = 0.5f * (rois[r * 5 + 1] + rois[r * 5 + 3]);
        const float cy = 0.5f * (rois[r * 5 + 2] + rois[r * 5 + 4]);
        const int tx = min(7, max(0, (int)(cx * 8.0f / iw)));
        const int ty = min(7, max(0, (int)(cy * 8.0f / ih)));
        const int bin = (lvl - 2) * 64 + ty * 8 + tx;
        myR[m] = r; myBin[m] = bin;
        mySlot[m] = atomicAdd(&cnt[bin], 1);
        ++m;
    }
    __syncthreads();

    const int v = (t < NBIN) ? cnt[t] : 0;
    if (t < NBIN) tmp[t] = v;
    __syncthreads();
    for (int s = 1; s < NBIN; s <<= 1) {
        const int u = (t < NBIN && t >= s) ? tmp[t - s] : 0;
        __syncthreads();
        if (t < NBIN) tmp[t] += u;
        __syncthreads();
    }
    if (t < NBIN) cnt[t] = tmp[t] - v;   // exclusive offsets, reuse cnt
    __syncthreads();

    for (int i = 0; i < m; ++i)
        sorted[cnt[myBin[i]] + mySlot[i]] = myR[i];
}

// ---- fused transpose, all levels: [C,HW] f32 -> [HW,C] fp16 ----
__global__ __launch_bounds__(256) void transpose_all_kernel(
    const float* __restrict__ p2, const float* __restrict__ p3,
    const float* __restrict__ p4, const float* __restrict__ p5,
    __half* __restrict__ t2, __half* __restrict__ t3,
    __half* __restrict__ t4, __half* __restrict__ t5,
    int HW2, int HW3, int HW4, int HW5)
{
    const int n2 = (HW2 / 64) * 4, n3 = (HW3 / 64) * 4, n4 = (HW4 / 64) * 4;
    int bid = blockIdx.x;
    const float* src; __half* dst; int HW;
    if (bid < n2)              { src = p2; dst = t2; HW = HW2; }
    else if ((bid -= n2) < n3) { src = p3; dst = t3; HW = HW3; }
    else if ((bid -= n3) < n4) { src = p4; dst = t4; HW = HW4; }
    else { bid -= n4;            src = p5; dst = t5; HW = HW5; }
    const int ptiles = HW / 64;
    const int pt = bid % ptiles, ct = bid / ptiles;
    const int pbase = pt * 64, cbase = ct * 64;
    const int t = threadIdx.x;

    __shared__ float tile[64][65];

    // read: 4 passes of 16 channels, float4 per lane (both coalesced)
    const int l = t & 15, cr = t >> 4;
#pragma unroll
    for (int p = 0; p < 4; ++p) {
        const int c = p * 16 + cr;
        const float4 v = *(const float4*)(src + (size_t)(cbase + c) * HW + pbase + l * 4);
        tile[c][l * 4 + 0] = v.x;
        tile[c][l * 4 + 1] = v.y;
        tile[c][l * 4 + 2] = v.z;
        tile[c][l * 4 + 3] = v.w;
    }
    __syncthreads();

    // write: 8 passes of 8 pixel-rows, half2 per lane (coalesced)
    const int ch2 = t & 31, pr = t >> 5;
#pragma unroll
    for (int p = 0; p < 8; ++p) {
        const int row = p * 8 + pr;
        const __half2 h = __floats2half2_rn(tile[ch2 * 2][row], tile[ch2 * 2 + 1][row]);
        *(__half2*)(dst + (size_t)(pbase + row) * CCH + cbase + ch2 * 2) = h;
    }
}

// ---- main kernel (transposed fp16 layout): block per RoI, lane = channel ----
__global__ __launch_bounds__(256) void fpn_main_t(
    const __half* __restrict__ t2, const __half* __restrict__ t3,
    const __half* __restrict__ t4, const __half* __restrict__ t5,
    const float* __restrict__ rois, const float* __restrict__ im_info,
    float* __restrict__ out, const int* __restrict__ order,
    int H2, int H3, int H4, int H5, int R)
{
    // bijective XCD chunk swizzle
    const int n = blockIdx.x;
    const int q = R / 8, rem = R % 8;
    const int xcd = n % 8, idx = n / 8;
    const int nsw = (xcd < rem ? xcd * (q + 1) : rem * (q + 1) + (xcd - rem) * q) + idx;
    const int r = order ? order[nsw] : nsw;
    const int t = threadIdx.x;   // channel

    const float x1 = rois[r * 5 + 1];
    const float y1 = rois[r * 5 + 2];
    const float x2 = rois[r * 5 + 3];
    const float y2 = rois[r * 5 + 4];

    const int lvl = roi_level(rois, r);
    const __half* feat;
    int H;
    switch (lvl) {
        case 2:  feat = t2; H = H2; break;
        case 3:  feat = t3; H = H3; break;
        case 4:  feat = t4; H = H4; break;
        default: feat = t5; H = H5; break;
    }
    const int W = H;

    // grid coords (exact numpy arithmetic on the index path)
    const float im_h  = im_info[0];
    const float scale = __fdiv_rn((float)H, im_h);
    const float ylo = __fmul_rn(y1, scale), yhi = __fmul_rn(y2, scale);
    const float xlo = __fmul_rn(x1, scale), xhi = __fmul_rn(x2, scale);

    float wy[GRIDG], wx[GRIDG];
    int yoff[GRIDG], dy[GRIDG], xoff[GRIDG], dx[GRIDG];
#pragma unroll
    for (int i = 0; i < GRIDG; ++i) {
        const float tf = __fdiv_rn((float)i, (float)(GRIDG - 1));
        float ty = __fadd_rn(ylo, __fmul_rn(__fsub_rn(yhi, ylo), tf));
        ty = fminf(fmaxf(ty, 0.0f), (float)(H - 1));
        const float y0f = floorf(ty);
        const int   y0  = (int)y0f;
        yoff[i] = y0 * W * CCH;
        dy[i]   = (min(y0 + 1, H - 1) - y0) * W * CCH;
        wy[i]   = __fsub_rn(ty, y0f);

        float tx = __fadd_rn(xlo, __fmul_rn(__fsub_rn(xhi, xlo), tf));
        tx = fminf(fmaxf(tx, 0.0f), (float)(W - 1));
        const float x0f = floorf(tx);
        const int   x0  = (int)x0f;
        xoff[i] = x0 * CCH;
        dx[i]   = (min(x0 + 1, W - 1) - x0) * CCH;
        wx[i]   = __fsub_rn(tx, x0f);
    }

    __shared__ float s_out[CCH * SPAD];   // 52 KB

    float rowPrev[GRIDG], rowCur[GRIDG];
#pragma unroll
    for (int gy = 0; gy < GRIDG; ++gy) {
        const __half* base = feat + yoff[gy] + t;
        const int dyg = dy[gy];
        const float wyg = wy[gy];
        const float omy = 1.0f - wyg;
#pragma unroll
        for (int gx = 0; gx < GRIDG; ++gx) {
            const __half* qp = base + xoff[gx];
            const int dxg = dx[gx];
            const float v00 = __half2float(qp[0]);
            const float v01 = __half2float(qp[dxg]);
            const float v10 = __half2float(qp[dyg]);
            const float v11 = __half2float(qp[dyg + dxg]);
            const float wxg = wx[gx];
            const float omx = 1.0f - wxg;
            rowCur[gx] = omy * (omx * v00 + wxg * v01) + wyg * (omx * v10 + wxg * v11);
        }
        if (gy > 0) {
            const int py = gy - 1;
#pragma unroll
            for (int px = 0; px < POOLSZ; ++px) {
                s_out[t * SPAD + py * POOLSZ + px] =
                    0.25f * (rowPrev[px] + rowPrev[px + 1] + rowCur[px] + rowCur[px + 1]);
            }
        }
#pragma unroll
        for (int gx = 0; gx < GRIDG; ++gx) rowPrev[gx] = rowCur[gx];
    }

    __syncthreads();
    float* obase = out + (size_t)r * (CCH * OPP);
#pragma unroll
    for (int i = 0; i < OPP; ++i) {
        const unsigned k = (unsigned)(i * CCH + t);
        const unsigned c = (k * 21400u) >> 20;        // k/49, exact for k<12544
        const unsigned pp = k - c * 49u;
        __builtin_nontemporal_store(s_out[c * SPAD + pp], obase + k);
    }
}

// ---- fallback (round-3 kernel): only if d_ws can't hold the fp16 copies ----
__global__ __launch_bounds__(256) void fpn_roialign_kernel(
    const float* __restrict__ p2, const float* __restrict__ p3,
    const float* __restrict__ p4, const float* __restrict__ p5,
    const float* __restrict__ rois, const float* __restrict__ im_info,
    float* __restrict__ out, const int* __restrict__ order,
    int H2, int H3, int H4, int H5, int R)
{
    const int n = blockIdx.x;
    const int q = R / 8, rem = R % 8;
    const int xcd = n % 8, idx = n / 8;
    const int nsw = (xcd < rem ? xcd * (q + 1) : rem * (q + 1) + (xcd - rem) * q) + idx;
    const int r = order ? order[nsw] : nsw;

    const float bf = rois[r * 5 + 0];
    const float x1 = rois[r * 5 + 1];
    const float y1 = rois[r * 5 + 2];
    const float x2 = rois[r * 5 + 3];
    const float y2 = rois[r * 5 + 4];

    const int lvl = roi_level(rois, r);
    const float* feat;
    int H;
    switch (lvl) {
        case 2:  feat = p2; H = H2; break;
        case 3:  feat = p3; H = H3; break;
        case 4:  feat = p4; H = H4; break;
        default: feat = p5; H = H5; break;
    }
    const int W = H;
    const int wv  = threadIdx.x >> 6;
    const int lid = threadIdx.x & 63;
    const int gy  = lid >> 3;
    const int gx  = lid & 7;

    const float im_h  = im_info[0];
    const float scale = __fdiv_rn((float)H, im_h);
    const float ylo = __fmul_rn(y1, scale), yhi = __fmul_rn(y2, scale);
    const float xlo = __fmul_rn(x1, scale), xhi = __fmul_rn(x2, scale);
    float ty = __fadd_rn(ylo, __fmul_rn(__fsub_rn(yhi, ylo),
                                        __fdiv_rn((float)gy, (float)(GRIDG - 1))));
    ty = fminf(fmaxf(ty, 0.0f), (float)(H - 1));
    float tx = __fadd_rn(xlo, __fmul_rn(__fsub_rn(xhi, xlo),
                                        __fdiv_rn((float)gx, (float)(GRIDG - 1))));
    tx = fminf(fmaxf(tx, 0.0f), (float)(W - 1));
    const float y0f = floorf(ty), x0f = floorf(tx);
    const int   y0  = (int)y0f,   x0  = (int)x0f;
    const int   y1i = min(y0 + 1, H - 1);
    const int   x1i = min(x0 + 1, W - 1);
    const float wyv = __fsub_rn(ty, y0f);
    const float wxv = __fsub_rn(tx, x0f);
    const float omy = 1.0f - wyv;
    const float omx = 1.0f - wxv;

    const int b = (int)bf;
    const size_t plane = (size_t)H * W;
    const float* fbase = feat + (size_t)(b * CCH + wv * 64) * plane;
    const int o00 = y0  * W + x0;
    const int o01 = y0  * W + x1i;
    const int o10 = y1i * W + x0;
    const int o11 = y1i * W + x1i;

    float* obase = out + (size_t)r * (CCH * OPP) + (size_t)(wv * 64) * OPP;
    const bool wr  = (gy < POOLSZ) && (gx < POOLSZ);
    const int oidx = gy * POOLSZ + gx;

#pragma unroll 4
    for (int k = 0; k < 64; ++k) {
        const float* f = fbase + (size_t)k * plane;
        const float v00 = f[o00];
        const float v01 = f[o01];
        const float v10 = f[o10];
        const float v11 = f[o11];
        const float v = omy * (omx * v00 + wxv * v01) + wyv * (omx * v10 + wxv * v11);
        const float vb  = __shfl_down(v, 8);
        const float vr  = __shfl_down(v, 1);
        const float vbr = __shfl_down(v, 9);
        if (wr) obase[k * OPP + oidx] = 0.25f * (((v + vb) + vr) + vbr);
    }
}

extern "C" void kernel_launch(void* const* d_in, const int* in_sizes, int n_in,
                              void* d_out, int out_size, void* d_ws, size_t ws_size,
                              hipStream_t stream) {
    const float* p2      = (const float*)d_in[0];
    const float* p3      = (const float*)d_in[1];
    const float* p4      = (const float*)d_in[2];
    const float* p5      = (const float*)d_in[3];
    const float* rois    = (const float*)d_in[4];
    const float* im_info = (const float*)d_in[5];
    float* out = (float*)d_out;

    const int R = in_sizes[4] / 5;
    auto dimOf = [](int sz) {
        int hw = sz / CCH;
        return (int)(sqrtf((float)hw) + 0.5f);
    };
    const int H2 = dimOf(in_sizes[0]);
    const int H3 = dimOf(in_sizes[1]);
    const int H4 = dimOf(in_sizes[2]);
    const int H5 = dimOf(in_sizes[3]);
    const size_t HW2 = (size_t)H2 * H2, HW3 = (size_t)H3 * H3;
    const size_t HW4 = (size_t)H4 * H4, HW5 = (size_t)H5 * H5;

    // ws layout: sorted[R] ints | t2 | t3 | t4 | t5 (fp16, 256-byte aligned)
    const size_t sortBytes = (size_t)R * sizeof(int);
    const size_t sortPad   = (sortBytes + 255) & ~(size_t)255;
    const size_t transBytes = (HW2 + HW3 + HW4 + HW5) * CCH * sizeof(__half);
    const bool canSort  = (ws_size >= sortBytes) && (R <= 1024 * MAXPER);
    const bool canTrans = ws_size >= sortPad + transBytes;

    const int* order = nullptr;
    if (canSort) {
        int* sorted = (int*)d_ws;
        sort_all_kernel<<<1, 1024, 0, stream>>>(rois, im_info, R, sorted);
        order = sorted;
    }

    if (canTrans) {
        __half* t2 = (__half*)((char*)d_ws + sortPad);
        __half* t3 = t2 + HW2 * CCH;
        __half* t4 = t3 + HW3 * CCH;
        __half* t5 = t4 + HW4 * CCH;
        const unsigned nblk = (unsigned)((HW2 + HW3 + HW4 + HW5) / 64 * 4);
        transpose_all_kernel<<<nblk, 256, 0, stream>>>(
            p2, p3, p4, p5, t2, t3, t4, t5,
            (int)HW2, (int)HW3, (int)HW4, (int)HW5);
        fpn_main_t<<<R, 256, 0, stream>>>(
            t2, t3, t4, t5, rois, im_info, out, order, H2, H3, H4, H5, R);
    } else {
        fpn_roialign_kernel<<<R, 256, 0, stream>>>(
            p2, p3, p4, p5, rois, im_info, out, order, H2, H3, H4, H5, R);
    }
}